// Round 7
// baseline (1966.516 us; speedup 1.0000x reference)
//
#include <hip/hip_runtime.h>
#include <stdint.h>

#define TN_D 1024
#define TN_F 1024
#define SENT32 0xAAAAAAAAu
#define NBLK 64
#define CPB 16  // columns per block (1 per wave, 16 waves)

typedef _Float16 half8_t __attribute__((ext_vector_type(8)));

// ---------------------------------------------------------------------------
// Transpose + convert: core[s][i][j] f32 -> coreT[s][j][i] f16.
// ---------------------------------------------------------------------------
__global__ __launch_bounds__(256) void tn_transpose(const float* __restrict__ core,
                                                    _Float16* __restrict__ coreT) {
    __shared__ float tile[64][65];
    const int s = blockIdx.z;
    const size_t base = (size_t)s * TN_D * TN_D;
    const int j0 = blockIdx.x * 64;
    const int i0 = blockIdx.y * 64;
    const int tx = threadIdx.x;
    const int ty = threadIdx.y;
#pragma unroll
    for (int r = 0; r < 4; ++r) {
        const int ii = ty + 16 * r;
        const float4 v = *(const float4*)&core[base + (size_t)(i0 + ii) * TN_D + j0 + 4 * tx];
        tile[ii][4 * tx + 0] = v.x; tile[ii][4 * tx + 1] = v.y;
        tile[ii][4 * tx + 2] = v.z; tile[ii][4 * tx + 3] = v.w;
    }
    __syncthreads();
#pragma unroll
    for (int r = 0; r < 4; ++r) {
        const int jj = ty + 16 * r;
        _Float16 h4[4];
        h4[0] = (_Float16)tile[4 * tx + 0][jj];
        h4[1] = (_Float16)tile[4 * tx + 1][jj];
        h4[2] = (_Float16)tile[4 * tx + 2][jj];
        h4[3] = (_Float16)tile[4 * tx + 3][jj];
        *(uint64_t*)&coreT[base + (size_t)(j0 + jj) * TN_D + i0 + 4 * tx] = *(uint64_t*)h4;
    }
}

__device__ __forceinline__ uint32_t aload(const uint32_t* p) {
    return __hip_atomic_load(p, __ATOMIC_RELAXED, __HIP_MEMORY_SCOPE_AGENT);
}

// Depth-3 pipelined poll: keep 3 loads of *p in flight; check only the oldest
// (compiler emits s_waitcnt vmcnt(2)), refill each iteration. Steady-state
// completion spacing ~ lambda/3 instead of lambda -> mean detect delay after
// visibility drops from ~1.5*lambda to ~1.17*lambda. Same-address loads are
// monotone (sentinel -> value, write-once row), so any hit is valid.
__device__ __forceinline__ float poll3(const uint32_t* p) {
    uint32_t a = aload(p);
    uint32_t b = aload(p);
    uint32_t c = aload(p);
    while (a == SENT32) {
        a = b; b = c; c = aload(p);
    }
    return __uint_as_float(a);
}

__device__ __forceinline__ float dot8h(float4 a, float4 b, half8_t h) {
    return a.x * (float)h[0] + a.y * (float)h[1] + a.z * (float)h[2] + a.w * (float)h[3] +
           b.x * (float)h[4] + b.y * (float)h[5] + b.z * (float)h[6] + b.w * (float)h[7];
}

// ---------------------------------------------------------------------------
// Persistent chain, f16 matrix — EXACT R0 skeleton (best measured: 1637 us),
// single variable changed: poll1 -> poll3 (depth-3 pipelined detect).
// 64 blocks x 1024 threads (16 waves); wave w owns column j = 16*blk + w.
// Per step: each thread polls ONE dword of the previous v-row (agent
// atomics), writes it to LDS; one barrier; each wave dots its
// register-prefetched f16 column vs LDS v; lane0 deposits the result in
// sentinel-guarded volatile LDS; wave0 gathers all 16 and issues ONE
// coalesced 64B agent-store per block. The per-step __syncthreads orders
// the redv read/poison against next-step redv writes.
// ---------------------------------------------------------------------------
__global__ __launch_bounds__(1024, 1) void tn_chain_f16(const int* __restrict__ x,
                                                        const _Float16* __restrict__ mat,
                                                        const float* __restrict__ left,
                                                        const float* __restrict__ right,
                                                        float* __restrict__ vg,
                                                        float* __restrict__ out) {
    __shared__ float lv[2][TN_D];           // 8 KB double-buffered v
    __shared__ int xs[TN_F];                // 4 KB symbol stream
    volatile __shared__ uint32_t redv[CPB]; // per-wave results, sentinel-guarded
    __shared__ float red2[CPB];

    const int tid = threadIdx.x;
    const int w = tid >> 6;
    const int l = tid & 63;
    const int j = blockIdx.x * CPB + w;

    xs[tid] = x[tid];
    if (tid < CPB) redv[tid] = SENT32;
    __syncthreads();

    half8_t A0, A1, B0, B1;
    {
        const half8_t* cp = (const half8_t*)(mat + ((size_t)xs[0] * TN_D + j) * TN_D);
        A0 = cp[l]; A1 = cp[l + 64];
    }

    for (int t = 0; t < TN_F; t += 2) {
        const int s1 = xs[(t + 1 < TN_F) ? t + 1 : TN_F - 1];
        const int s2 = xs[(t + 2 < TN_F) ? t + 2 : TN_F - 1];

        // ================= even step t (registers A) =================
        if (t == 0) lv[0][tid] = left[tid];
        else        lv[0][tid] = poll3((const uint32_t*)vg + (size_t)(t - 1) * TN_D + tid);
        __syncthreads();
        {   // prefetch col for t+1 (drained only at the NEXT barrier, a step away)
            const half8_t* cp = (const half8_t*)(mat + ((size_t)s1 * TN_D + j) * TN_D);
            B0 = cp[l]; B1 = cp[l + 64];
        }
        {
            const float4* vv = (const float4*)lv[0];
            float acc = dot8h(vv[2 * l], vv[2 * l + 1], A0) +
                        dot8h(vv[2 * l + 128], vv[2 * l + 129], A1);
#pragma unroll
            for (int off = 32; off; off >>= 1) acc += __shfl_down(acc, off, 64);
            if (l == 0) {
                __asm__ volatile("" ::: "memory");
                redv[w] = __float_as_uint(acc);
            }
            if (w == 0 && l < CPB) {
                uint32_t u = redv[l];
                while (u == SENT32) u = redv[l];
                redv[l] = SENT32;  // re-poison BEFORE the store becomes visible
                __asm__ volatile("" ::: "memory");
                __hip_atomic_store((uint32_t*)vg + (size_t)t * TN_D + blockIdx.x * CPB + l,
                                   u, __ATOMIC_RELAXED, __HIP_MEMORY_SCOPE_AGENT);
            }
        }

        // ================= odd step t+1 (registers B) =================
        lv[1][tid] = poll3((const uint32_t*)vg + (size_t)t * TN_D + tid);
        __syncthreads();
        {   // prefetch col for t+2
            const half8_t* cp = (const half8_t*)(mat + ((size_t)s2 * TN_D + j) * TN_D);
            A0 = cp[l]; A1 = cp[l + 64];
        }
        {
            const float4* vv = (const float4*)lv[1];
            float acc = dot8h(vv[2 * l], vv[2 * l + 1], B0) +
                        dot8h(vv[2 * l + 128], vv[2 * l + 129], B1);
#pragma unroll
            for (int off = 32; off; off >>= 1) acc += __shfl_down(acc, off, 64);
            if (l == 0) {
                __asm__ volatile("" ::: "memory");
                redv[w] = __float_as_uint(acc);
            }
            if (w == 0 && l < CPB) {
                uint32_t u = redv[l];
                while (u == SENT32) u = redv[l];
                redv[l] = SENT32;
                __asm__ volatile("" ::: "memory");
                __hip_atomic_store((uint32_t*)vg + (size_t)(t + 1) * TN_D + blockIdx.x * CPB + l,
                                   u, __ATOMIC_RELAXED, __HIP_MEMORY_SCOPE_AGENT);
            }
        }
    }

    // ---- final dot with right boundary: block 0 ----
    if (blockIdx.x == 0) {
        float v = poll3((const uint32_t*)vg + (size_t)(TN_F - 1) * TN_D + tid);
        float p = v * right[tid];
#pragma unroll
        for (int off = 32; off; off >>= 1) p += __shfl_down(p, off, 64);
        if (l == 0) red2[w] = p;
        __syncthreads();
        if (tid == 0) {
            float s = 0.f;
#pragma unroll
            for (int k = 0; k < CPB; ++k) s += red2[k];
            out[0] = s;
        }
    }
}

// ---------------------------------------------------------------------------
// Fallback (tiny workspace): R2-structure fp32, no transpose.
// ---------------------------------------------------------------------------
__device__ __forceinline__ float4 poll4(const uint32_t* vp) {
    const unsigned long long* p = (const unsigned long long*)vp;
    unsigned long long a = __hip_atomic_load(p, __ATOMIC_RELAXED, __HIP_MEMORY_SCOPE_AGENT);
    unsigned long long b = __hip_atomic_load(p + 1, __ATOMIC_RELAXED, __HIP_MEMORY_SCOPE_AGENT);
    while ((uint32_t)a == SENT32 || (uint32_t)(a >> 32) == SENT32)
        a = __hip_atomic_load(p, __ATOMIC_RELAXED, __HIP_MEMORY_SCOPE_AGENT);
    while ((uint32_t)b == SENT32 || (uint32_t)(b >> 32) == SENT32)
        b = __hip_atomic_load(p + 1, __ATOMIC_RELAXED, __HIP_MEMORY_SCOPE_AGENT);
    return make_float4(__uint_as_float((uint32_t)a), __uint_as_float((uint32_t)(a >> 32)),
                       __uint_as_float((uint32_t)b), __uint_as_float((uint32_t)(b >> 32)));
}

__global__ __launch_bounds__(256, 1) void tn_chain_f32(const int* __restrict__ x,
                                                       const float* __restrict__ mat,
                                                       const float* __restrict__ left,
                                                       const float* __restrict__ right,
                                                       float* __restrict__ vg,
                                                       float* __restrict__ out) {
    __shared__ float4 lv[2][TN_D / 4];
    __shared__ float red[4];
    const int tid = threadIdx.x;
    const int w = tid >> 6;
    const int l = tid & 63;
    const int j = blockIdx.x * 4 + w;

    for (int t = 0; t < TN_F; ++t) {
        if (t == 0) lv[0][tid] = ((const float4*)left)[tid];
        else lv[t & 1][tid] = poll4((const uint32_t*)vg + (size_t)(t - 1) * TN_D + 4 * tid);
        __syncthreads();
        const float* mp = mat + (size_t)x[t] * TN_D * TN_D + j;
        const float4* vv = lv[t & 1];
        float acc = 0.f;
#pragma unroll
        for (int k = 0; k < 4; ++k) {
            const int i = 4 * l + 256 * k;
            const float4 v = vv[l + 64 * k];
            acc += v.x * mp[(size_t)i * TN_D] + v.y * mp[(size_t)(i + 1) * TN_D] +
                   v.z * mp[(size_t)(i + 2) * TN_D] + v.w * mp[(size_t)(i + 3) * TN_D];
        }
#pragma unroll
        for (int off = 32; off; off >>= 1) acc += __shfl_down(acc, off, 64);
        if (l == 0)
            __hip_atomic_store((uint32_t*)vg + (size_t)t * TN_D + j, __float_as_uint(acc),
                               __ATOMIC_RELAXED, __HIP_MEMORY_SCOPE_AGENT);
    }
    if (blockIdx.x == 0) {
        float4 v = poll4((const uint32_t*)vg + (size_t)(TN_F - 1) * TN_D + 4 * tid);
        const float4 r4 = ((const float4*)right)[tid];
        float p = v.x * r4.x + v.y * r4.y + v.z * r4.z + v.w * r4.w;
#pragma unroll
        for (int off = 32; off; off >>= 1) p += __shfl_down(p, off, 64);
        if (l == 0) red[w] = p;
        __syncthreads();
        if (tid == 0) out[0] = red[0] + red[1] + red[2] + red[3];
    }
}

extern "C" void kernel_launch(void* const* d_in, const int* in_sizes, int n_in,
                              void* d_out, int out_size, void* d_ws, size_t ws_size,
                              hipStream_t stream) {
    const int* x = (const int*)d_in[0];
    const float* core = (const float*)d_in[1];
    const float* left = (const float*)d_in[2];
    const float* right = (const float*)d_in[3];
    float* out = (float*)d_out;

    const int nsym = in_sizes[1] / (TN_D * TN_D);
    const size_t coreTBytes = (size_t)in_sizes[1] * sizeof(_Float16);  // 64 MB
    const size_t vbufBytes = (size_t)TN_F * TN_D * sizeof(float);      // 4 MB

    if (ws_size >= coreTBytes + vbufBytes) {
        _Float16* coreT = (_Float16*)d_ws;
        float* vg = (float*)((char*)d_ws + coreTBytes);
        hipMemsetAsync(vg, 0xAA, vbufBytes, stream);
        tn_transpose<<<dim3(16, 16, nsym), dim3(16, 16), 0, stream>>>(core, coreT);
        tn_chain_f16<<<NBLK, 1024, 0, stream>>>(x, coreT, left, right, vg, out);
    } else {
        float* vg = (float*)d_ws;
        hipMemsetAsync(vg, 0xAA, vbufBytes, stream);
        tn_chain_f32<<<256, 256, 0, stream>>>(x, core, left, right, vg, out);
    }
}

// Round 8
// 1834.902 us; speedup vs baseline: 1.0717x; 1.0717x over previous
//
#include <hip/hip_runtime.h>
#include <stdint.h>

#define TN_D 1024
#define TN_F 1024
#define SENT32 0xAAAAAAAAu
#define NBLK 64
#define CPB 16  // columns per block (1 per wave, 16 waves)

typedef _Float16 half8_t __attribute__((ext_vector_type(8)));

// ---------------------------------------------------------------------------
// Transpose + convert: core[s][i][j] f32 -> coreT[s][j][i] f16.
// ---------------------------------------------------------------------------
__global__ __launch_bounds__(256) void tn_transpose(const float* __restrict__ core,
                                                    _Float16* __restrict__ coreT) {
    __shared__ float tile[64][65];
    const int s = blockIdx.z;
    const size_t base = (size_t)s * TN_D * TN_D;
    const int j0 = blockIdx.x * 64;
    const int i0 = blockIdx.y * 64;
    const int tx = threadIdx.x;
    const int ty = threadIdx.y;
#pragma unroll
    for (int r = 0; r < 4; ++r) {
        const int ii = ty + 16 * r;
        const float4 v = *(const float4*)&core[base + (size_t)(i0 + ii) * TN_D + j0 + 4 * tx];
        tile[ii][4 * tx + 0] = v.x; tile[ii][4 * tx + 1] = v.y;
        tile[ii][4 * tx + 2] = v.z; tile[ii][4 * tx + 3] = v.w;
    }
    __syncthreads();
#pragma unroll
    for (int r = 0; r < 4; ++r) {
        const int jj = ty + 16 * r;
        _Float16 h4[4];
        h4[0] = (_Float16)tile[4 * tx + 0][jj];
        h4[1] = (_Float16)tile[4 * tx + 1][jj];
        h4[2] = (_Float16)tile[4 * tx + 2][jj];
        h4[3] = (_Float16)tile[4 * tx + 3][jj];
        *(uint64_t*)&coreT[base + (size_t)(j0 + jj) * TN_D + i0 + 4 * tx] = *(uint64_t*)h4;
    }
}

// Spin until dword at p != sentinel (0xAA poison; true values are positive).
__device__ __forceinline__ float poll1(const uint32_t* p) {
    uint32_t u = __hip_atomic_load(p, __ATOMIC_RELAXED, __HIP_MEMORY_SCOPE_AGENT);
    while (u == SENT32)
        u = __hip_atomic_load(p, __ATOMIC_RELAXED, __HIP_MEMORY_SCOPE_AGENT);
    return __uint_as_float(u);
}

__device__ __forceinline__ float dot8h(float4 a, float4 b, half8_t h) {
    return a.x * (float)h[0] + a.y * (float)h[1] + a.z * (float)h[2] + a.w * (float)h[3] +
           b.x * (float)h[4] + b.y * (float)h[5] + b.z * (float)h[6] + b.w * (float)h[7];
}

// ---------------------------------------------------------------------------
// Persistent chain, f16 matrix. 64 blocks x 1024 threads (16 waves); wave w
// owns column j = 16*blk + w. Per step: each thread polls ONE dword of the
// previous v-row (agent atomics), writes it to LDS; one barrier; each wave
// dots its register-prefetched f16 column vs LDS v; lane0 deposits the
// result in sentinel-guarded volatile LDS (pure ds ops, no fences); wave 0
// gathers all 16 and issues ONE coalesced 64B agent-store per block.
// The per-step __syncthreads orders the redv read/poison against next-step
// redv writes (waves cannot pass the barrier until wave0 finished reading).
// ---------------------------------------------------------------------------
__global__ __launch_bounds__(1024, 1) void tn_chain_f16(const int* __restrict__ x,
                                                        const _Float16* __restrict__ mat,
                                                        const float* __restrict__ left,
                                                        const float* __restrict__ right,
                                                        float* __restrict__ vg,
                                                        float* __restrict__ out) {
    __shared__ float lv[2][TN_D];           // 8 KB double-buffered v
    __shared__ int xs[TN_F];                // 4 KB symbol stream
    volatile __shared__ uint32_t redv[CPB]; // per-wave results, sentinel-guarded
    __shared__ float red2[CPB];

    const int tid = threadIdx.x;
    const int w = tid >> 6;
    const int l = tid & 63;
    const int j = blockIdx.x * CPB + w;

    xs[tid] = x[tid];
    if (tid < CPB) redv[tid] = SENT32;
    __syncthreads();

    half8_t A0, A1, B0, B1;
    {
        const half8_t* cp = (const half8_t*)(mat + ((size_t)xs[0] * TN_D + j) * TN_D);
        A0 = cp[l]; A1 = cp[l + 64];
    }

    for (int t = 0; t < TN_F; t += 2) {
        const int s1 = xs[(t + 1 < TN_F) ? t + 1 : TN_F - 1];
        const int s2 = xs[(t + 2 < TN_F) ? t + 2 : TN_F - 1];

        // ================= even step t (registers A) =================
        if (t == 0) lv[0][tid] = left[tid];
        else        lv[0][tid] = poll1((const uint32_t*)vg + (size_t)(t - 1) * TN_D + tid);
        __syncthreads();
        {   // prefetch col for t+1 (drained only at the NEXT barrier, a step away)
            const half8_t* cp = (const half8_t*)(mat + ((size_t)s1 * TN_D + j) * TN_D);
            B0 = cp[l]; B1 = cp[l + 64];
        }
        {
            const float4* vv = (const float4*)lv[0];
            float acc = dot8h(vv[2 * l], vv[2 * l + 1], A0) +
                        dot8h(vv[2 * l + 128], vv[2 * l + 129], A1);
#pragma unroll
            for (int off = 32; off; off >>= 1) acc += __shfl_down(acc, off, 64);
            if (l == 0) {
                __asm__ volatile("" ::: "memory");
                redv[w] = __float_as_uint(acc);
            }
            if (w == 0 && l < CPB) {
                uint32_t u = redv[l];
                while (u == SENT32) u = redv[l];
                redv[l] = SENT32;  // re-poison BEFORE the store becomes visible
                __asm__ volatile("" ::: "memory");
                __hip_atomic_store((uint32_t*)vg + (size_t)t * TN_D + blockIdx.x * CPB + l,
                                   u, __ATOMIC_RELAXED, __HIP_MEMORY_SCOPE_AGENT);
            }
        }

        // ================= odd step t+1 (registers B) =================
        lv[1][tid] = poll1((const uint32_t*)vg + (size_t)t * TN_D + tid);
        __syncthreads();
        {   // prefetch col for t+2
            const half8_t* cp = (const half8_t*)(mat + ((size_t)s2 * TN_D + j) * TN_D);
            A0 = cp[l]; A1 = cp[l + 64];
        }
        {
            const float4* vv = (const float4*)lv[1];
            float acc = dot8h(vv[2 * l], vv[2 * l + 1], B0) +
                        dot8h(vv[2 * l + 128], vv[2 * l + 129], B1);
#pragma unroll
            for (int off = 32; off; off >>= 1) acc += __shfl_down(acc, off, 64);
            if (l == 0) {
                __asm__ volatile("" ::: "memory");
                redv[w] = __float_as_uint(acc);
            }
            if (w == 0 && l < CPB) {
                uint32_t u = redv[l];
                while (u == SENT32) u = redv[l];
                redv[l] = SENT32;
                __asm__ volatile("" ::: "memory");
                __hip_atomic_store((uint32_t*)vg + (size_t)(t + 1) * TN_D + blockIdx.x * CPB + l,
                                   u, __ATOMIC_RELAXED, __HIP_MEMORY_SCOPE_AGENT);
            }
        }
    }

    // ---- final dot with right boundary: block 0 ----
    if (blockIdx.x == 0) {
        float v = poll1((const uint32_t*)vg + (size_t)(TN_F - 1) * TN_D + tid);
        float p = v * right[tid];
#pragma unroll
        for (int off = 32; off; off >>= 1) p += __shfl_down(p, off, 64);
        if (l == 0) red2[w] = p;
        __syncthreads();
        if (tid == 0) {
            float s = 0.f;
#pragma unroll
            for (int k = 0; k < CPB; ++k) s += red2[k];
            out[0] = s;
        }
    }
}

// ---------------------------------------------------------------------------
// Fallback (tiny workspace): R2-structure fp32, no transpose.
// ---------------------------------------------------------------------------
__device__ __forceinline__ float4 poll4(const uint32_t* vp) {
    const unsigned long long* p = (const unsigned long long*)vp;
    unsigned long long a = __hip_atomic_load(p, __ATOMIC_RELAXED, __HIP_MEMORY_SCOPE_AGENT);
    unsigned long long b = __hip_atomic_load(p + 1, __ATOMIC_RELAXED, __HIP_MEMORY_SCOPE_AGENT);
    while ((uint32_t)a == SENT32 || (uint32_t)(a >> 32) == SENT32)
        a = __hip_atomic_load(p, __ATOMIC_RELAXED, __HIP_MEMORY_SCOPE_AGENT);
    while ((uint32_t)b == SENT32 || (uint32_t)(b >> 32) == SENT32)
        b = __hip_atomic_load(p + 1, __ATOMIC_RELAXED, __HIP_MEMORY_SCOPE_AGENT);
    return make_float4(__uint_as_float((uint32_t)a), __uint_as_float((uint32_t)(a >> 32)),
                       __uint_as_float((uint32_t)b), __uint_as_float((uint32_t)(b >> 32)));
}

__global__ __launch_bounds__(256, 1) void tn_chain_f32(const int* __restrict__ x,
                                                       const float* __restrict__ mat,
                                                       const float* __restrict__ left,
                                                       const float* __restrict__ right,
                                                       float* __restrict__ vg,
                                                       float* __restrict__ out) {
    __shared__ float4 lv[2][TN_D / 4];
    __shared__ float red[4];
    const int tid = threadIdx.x;
    const int w = tid >> 6;
    const int l = tid & 63;
    const int j = blockIdx.x * 4 + w;

    for (int t = 0; t < TN_F; ++t) {
        if (t == 0) lv[0][tid] = ((const float4*)left)[tid];
        else lv[t & 1][tid] = poll4((const uint32_t*)vg + (size_t)(t - 1) * TN_D + 4 * tid);
        __syncthreads();
        const float* mp = mat + (size_t)x[t] * TN_D * TN_D + j;
        const float4* vv = lv[t & 1];
        float acc = 0.f;
#pragma unroll
        for (int k = 0; k < 4; ++k) {
            const int i = 4 * l + 256 * k;
            const float4 v = vv[l + 64 * k];
            acc += v.x * mp[(size_t)i * TN_D] + v.y * mp[(size_t)(i + 1) * TN_D] +
                   v.z * mp[(size_t)(i + 2) * TN_D] + v.w * mp[(size_t)(i + 3) * TN_D];
        }
#pragma unroll
        for (int off = 32; off; off >>= 1) acc += __shfl_down(acc, off, 64);
        if (l == 0)
            __hip_atomic_store((uint32_t*)vg + (size_t)t * TN_D + j, __float_as_uint(acc),
                               __ATOMIC_RELAXED, __HIP_MEMORY_SCOPE_AGENT);
    }
    if (blockIdx.x == 0) {
        float4 v = poll4((const uint32_t*)vg + (size_t)(TN_F - 1) * TN_D + 4 * tid);
        const float4 r4 = ((const float4*)right)[tid];
        float p = v.x * r4.x + v.y * r4.y + v.z * r4.z + v.w * r4.w;
#pragma unroll
        for (int off = 32; off; off >>= 1) p += __shfl_down(p, off, 64);
        if (l == 0) red[w] = p;
        __syncthreads();
        if (tid == 0) out[0] = red[0] + red[1] + red[2] + red[3];
    }
}

extern "C" void kernel_launch(void* const* d_in, const int* in_sizes, int n_in,
                              void* d_out, int out_size, void* d_ws, size_t ws_size,
                              hipStream_t stream) {
    const int* x = (const int*)d_in[0];
    const float* core = (const float*)d_in[1];
    const float* left = (const float*)d_in[2];
    const float* right = (const float*)d_in[3];
    float* out = (float*)d_out;

    const int nsym = in_sizes[1] / (TN_D * TN_D);
    const size_t coreTBytes = (size_t)in_sizes[1] * sizeof(_Float16);  // 64 MB
    const size_t vbufBytes = (size_t)TN_F * TN_D * sizeof(float);      // 4 MB

    if (ws_size >= coreTBytes + vbufBytes) {
        _Float16* coreT = (_Float16*)d_ws;
        float* vg = (float*)((char*)d_ws + coreTBytes);
        hipMemsetAsync(vg, 0xAA, vbufBytes, stream);
        tn_transpose<<<dim3(16, 16, nsym), dim3(16, 16), 0, stream>>>(core, coreT);
        tn_chain_f16<<<NBLK, 1024, 0, stream>>>(x, coreT, left, right, vg, out);
    } else {
        float* vg = (float*)d_ws;
        hipMemsetAsync(vg, 0xAA, vbufBytes, stream);
        tn_chain_f32<<<256, 256, 0, stream>>>(x, core, left, right, vg, out);
    }
}